// Round 2
// baseline (508.920 us; speedup 1.0000x reference)
//
#include <hip/hip_runtime.h>

typedef __bf16 bf16_t;
typedef __bf16 bf16x8 __attribute__((ext_vector_type(8)));
typedef float f32x4 __attribute__((ext_vector_type(4)));

#define B_TOTAL 262144
#define OUTC 324
#define ROWS 32

// d_ws layout (bf16 element offsets)
#define OFF_WIN   0        // [64][32]
#define OFF_WG    2048     // [256][256] gate-major: n = g*64 + j
#define OFF_WM1   67584    // [4][112][64]
#define OFF_WM2   96256    // [4][32][128]
#define OFF_WU1   112640   // [112][64]
#define OFF_WU2   119808   // [112][128]
#define OFF_WU3   134144   // [64][128]
#define OFF_WMV   142336   // [32][64]  (mu rows 0:16, var rows 16:32)
#define BF16_TOTAL 144384
// f32 combined gate bias bg[256] at byte offset BF16_TOTAL*2

__global__ void prep_kernel(const float* W_in, const float* msg_W1, const float* msg_W2,
                            const float* W_ih, const float* W_hh, const float* b_ih, const float* b_hh,
                            const float* W_u1, const float* W_u2, const float* W_u3,
                            const float* W_mu, const float* W_var,
                            bf16_t* wb, float* bg) {
  int tid = blockIdx.x * blockDim.x + threadIdx.x;
  int nth = gridDim.x * blockDim.x;
  for (int i = tid; i < 2048; i += nth) wb[OFF_WIN + i] = (bf16_t)W_in[i];
  for (int i = tid; i < 65536; i += nth) {
    int n = i >> 8, k = i & 255;
    int g = n >> 6, j = n & 63;
    float v = 0.f;
    if (j < 50) {
      int r = g * 50 + j;
      if (k < 192) v = W_ih[r * 192 + k];
      else if (k < 242) v = W_hh[r * 50 + (k - 192)];
    }
    wb[OFF_WG + i] = (bf16_t)v;
  }
  for (int i = tid; i < 256; i += nth) {
    int g = i >> 6, j = i & 63;
    bg[i] = (j < 50) ? (b_ih[g * 50 + j] + b_hh[g * 50 + j]) : 0.f;
  }
  for (int i = tid; i < 4 * 112 * 64; i += nth) {
    int p = i / (112 * 64); int rem = i % (112 * 64); int n = rem >> 6, k = rem & 63;
    wb[OFF_WM1 + i] = (bf16_t)((n < 100) ? msg_W1[(p * 100 + n) * 64 + k] : 0.f);
  }
  for (int i = tid; i < 4 * 32 * 128; i += nth) {
    int p = i / (32 * 128); int rem = i % (32 * 128); int n = rem >> 7, k = rem & 127;
    wb[OFF_WM2 + i] = (bf16_t)((k < 100) ? msg_W2[(p * 32 + n) * 100 + k] : 0.f);
  }
  for (int i = tid; i < 112 * 64; i += nth) {
    int n = i >> 6, k = i & 63;
    wb[OFF_WU1 + i] = (bf16_t)((n < 100 && k < 50) ? W_u1[n * 50 + k] : 0.f);
  }
  for (int i = tid; i < 112 * 128; i += nth) {
    int n = i >> 7, k = i & 127;
    wb[OFF_WU2 + i] = (bf16_t)((n < 100 && k < 100) ? W_u2[n * 100 + k] : 0.f);
  }
  for (int i = tid; i < 64 * 128; i += nth) {
    int n = i >> 7, k = i & 127;
    wb[OFF_WU3 + i] = (bf16_t)((k < 100) ? W_u3[n * 100 + k] : 0.f);
  }
  for (int i = tid; i < 32 * 64; i += nth) {
    int n = i >> 6, k = i & 63;
    wb[OFF_WMV + i] = (bf16_t)((n < 16) ? W_mu[n * 64 + k] : W_var[(n - 16) * 64 + k]);
  }
}

#define MFMA(a, b, c) __builtin_amdgcn_mfma_f32_16x16x32_bf16((a), (b), (c), 0, 0, 0)

__device__ __forceinline__ float frcp(float x) { return __builtin_amdgcn_rcpf(x); }
__device__ __forceinline__ float fsigmoid(float x) { return frcp(1.f + __expf(-x)); }
__device__ __forceinline__ float ftanh_f(float x) { return 1.f - 2.f * frcp(1.f + __expf(2.f * x)); }
__device__ __forceinline__ float fsoftplus(float x) { return (x > 15.f) ? x : __logf(1.f + __expf(x)); }

// LDS strides (elements): hm 264, t1 136, hn 72
__global__ __launch_bounds__(256, 4) void fused_kernel(
    const float* __restrict__ obs, const float* __restrict__ msg_in,
    const float* __restrict__ h_lstm, const float* __restrict__ c_lstm,
    const float* __restrict__ b_in, const float* __restrict__ msg_b1,
    const float* __restrict__ msg_b2, const float* __restrict__ b_u1,
    const float* __restrict__ b_u2, const float* __restrict__ b_u3,
    const float* __restrict__ b_mu, const float* __restrict__ b_var,
    const float* __restrict__ maxlv, const float* __restrict__ minlv,
    const bf16_t* __restrict__ wb, const float* __restrict__ bg,
    float* __restrict__ out) {
  __shared__ __align__(16) bf16_t hm[ROWS * 264];  // 0:64 x | 64:192 agg->h2b | 192:242 h | 242:256 zero
  __shared__ __align__(16) bf16_t t1[ROWS * 136];  // obs overlay -> m1 -> h2a -> h2
  __shared__ __align__(16) bf16_t hn[ROWS * 72];

  const int tid = threadIdx.x;
  const int row0 = blockIdx.x * ROWS;
  const int lane = tid & 63;
  const int w = tid >> 6;
  const int lr = lane & 15;
  const int kq = lane >> 4;
  bf16_t* obs_l = t1;  // stride 40

  // ---- Stage 0: stage inputs into LDS as bf16 (vector writes) ----
  if (tid < 128) {
    int base = tid * 8;
    int row = base >> 5, col = base & 31;
    const float4* s = (const float4*)(obs + (size_t)row0 * 32 + base);
    float4 v0 = s[0], v1 = s[1];
    bf16x8 pk;
    pk[0] = (bf16_t)v0.x; pk[1] = (bf16_t)v0.y; pk[2] = (bf16_t)v0.z; pk[3] = (bf16_t)v0.w;
    pk[4] = (bf16_t)v1.x; pk[5] = (bf16_t)v1.y; pk[6] = (bf16_t)v1.z; pk[7] = (bf16_t)v1.w;
    *(bf16x8*)(obs_l + row * 40 + col) = pk;
  }
  {
    int i = tid * 16;
    int p = i >> 10, rem = i & 1023;
    int row = rem >> 5, col = rem & 31;  // col in {0,16}
    const float4* s = (const float4*)(msg_in + (size_t)p * B_TOTAL * 32 + (size_t)(row0 + row) * 32 + col);
    float4 v0 = s[0], v1 = s[1], v2 = s[2], v3 = s[3];
    bf16x8 a, b;
    a[0] = (bf16_t)v0.x; a[1] = (bf16_t)v0.y; a[2] = (bf16_t)v0.z; a[3] = (bf16_t)v0.w;
    a[4] = (bf16_t)v1.x; a[5] = (bf16_t)v1.y; a[6] = (bf16_t)v1.z; a[7] = (bf16_t)v1.w;
    b[0] = (bf16_t)v2.x; b[1] = (bf16_t)v2.y; b[2] = (bf16_t)v2.z; b[3] = (bf16_t)v2.w;
    b[4] = (bf16_t)v3.x; b[5] = (bf16_t)v3.y; b[6] = (bf16_t)v3.z; b[7] = (bf16_t)v3.w;
    bf16_t* d = hm + row * 264 + 64 + p * 32 + col;
    *(bf16x8*)d = a;
    *(bf16x8*)(d + 8) = b;
  }
  {
    int i = tid * 8;
    int row = i >> 6, c0 = i & 63;
    const float* s = h_lstm + (size_t)(row0 + row) * 50 + c0;
    bf16x8 pk;
#pragma unroll
    for (int q = 0; q < 8; q++) {
      float v = 0.f;
      if (c0 + q < 50) v = s[q];
      pk[q] = (bf16_t)v;
    }
    *(bf16x8*)(hm + row * 264 + 192 + c0) = pk;
  }
  __syncthreads();

  // ---- Stage 1: x = relu(obs @ W_in^T + b_in) -> hm[:,0:64] ----
  {
    int nb = w * 16;
    float bv = b_in[nb + lr];
    bf16x8 B0 = *(const bf16x8*)(wb + OFF_WIN + (nb + lr) * 32 + kq * 8);
#pragma unroll
    for (int m = 0; m < 2; m++) {
      bf16x8 A0 = *(const bf16x8*)(obs_l + (m * 16 + lr) * 40 + kq * 8);
      f32x4 acc = {bv, bv, bv, bv};
      acc = MFMA(A0, B0, acc);
#pragma unroll
      for (int rr = 0; rr < 4; rr++)
        hm[(m * 16 + kq * 4 + rr) * 264 + nb + lr] = (bf16_t)fmaxf(acc[rr], 0.f);
    }
  }
  __syncthreads();

  // zero t1 pad cols 112:128 (obs overlay dead; visible by next barrier)
  if (tid < 64) {
    int row = tid >> 1, c = 112 + (tid & 1) * 8;
    bf16x8 z = {};
    *(bf16x8*)(t1 + row * 136 + c) = z;
  }

  // hoist x A-fragments (port-invariant)
  bf16x8 ax[2][2];
#pragma unroll
  for (int m = 0; m < 2; m++)
#pragma unroll
    for (int k = 0; k < 2; k++)
      ax[m][k] = *(const bf16x8*)(hm + (m * 16 + lr) * 264 + kq * 8 + k * 32);

  // ---- Stages 2/3 per port ----
  for (int p = 0; p < 4; p++) {
    for (int nt = w; nt < 7; nt += 4) {
      int nb = nt * 16;
      float bv = (nb + lr < 100) ? msg_b1[p * 100 + nb + lr] : 0.f;
      const bf16_t* Bp = wb + OFF_WM1 + p * 112 * 64 + (nb + lr) * 64 + kq * 8;
      bf16x8 b0 = *(const bf16x8*)Bp;
      bf16x8 b1 = *(const bf16x8*)(Bp + 32);
#pragma unroll
      for (int m = 0; m < 2; m++) {
        f32x4 acc = {bv, bv, bv, bv};
        acc = MFMA(ax[m][0], b0, acc);
        acc = MFMA(ax[m][1], b1, acc);
#pragma unroll
        for (int rr = 0; rr < 4; rr++)
          t1[(m * 16 + kq * 4 + rr) * 136 + nb + lr] = (bf16_t)fmaxf(acc[rr], 0.f);
      }
    }
    __syncthreads();
    {
      int nt = w & 1, m = w >> 1;
      int nb = nt * 16;
      float bv = msg_b2[p * 32 + nb + lr];
      const bf16_t* Bp = wb + OFF_WM2 + p * 32 * 128 + (nb + lr) * 128 + kq * 8;
      f32x4 acc = {bv, bv, bv, bv};
#pragma unroll
      for (int k = 0; k < 4; k++) {
        bf16x8 a = *(const bf16x8*)(t1 + (m * 16 + lr) * 136 + kq * 8 + k * 32);
        bf16x8 b = *(const bf16x8*)(Bp + k * 32);
        acc = MFMA(a, b, acc);
      }
#pragma unroll
      for (int rr = 0; rr < 4; rr++) {
        size_t row = row0 + m * 16 + kq * 4 + rr;
        out[row * OUTC + 32 + p * 32 + nb + lr] = acc[rr];
      }
    }
    __syncthreads();
  }

  // ---- Stage 4: gates + LSTM cell. wave w owns j = 16w+lr for all 4 gates ----
  {
    const int j = w * 16 + lr;
    float c_pre[2][4];
#pragma unroll
    for (int m = 0; m < 2; m++)
#pragma unroll
      for (int rr = 0; rr < 4; rr++) {
        size_t row = row0 + m * 16 + kq * 4 + rr;
        float cv = 0.f;
        if (j < 50) cv = c_lstm[row * 50 + j];
        c_pre[m][rr] = cv;
      }
    float bb0 = bg[j], bb1 = bg[64 + j], bb2 = bg[128 + j], bb3 = bg[192 + j];
#pragma unroll
    for (int m = 0; m < 2; m++) {
      bf16x8 a[8];
#pragma unroll
      for (int k = 0; k < 8; k++)
        a[k] = *(const bf16x8*)(hm + (m * 16 + lr) * 264 + kq * 8 + k * 32);
      f32x4 ai = {bb0, bb0, bb0, bb0}, af = {bb1, bb1, bb1, bb1};
      f32x4 ag = {bb2, bb2, bb2, bb2}, ao = {bb3, bb3, bb3, bb3};
#pragma unroll
      for (int g = 0; g < 4; g++) {
        bf16x8 bfr[8];
#pragma unroll
        for (int k = 0; k < 8; k++)
          bfr[k] = *(const bf16x8*)(wb + OFF_WG + (size_t)(g * 64 + j) * 256 + kq * 8 + k * 32);
        f32x4* accp = (g == 0) ? &ai : (g == 1) ? &af : (g == 2) ? &ag : &ao;
        f32x4 acc = *accp;
#pragma unroll
        for (int k = 0; k < 8; k++) acc = MFMA(a[k], bfr[k], acc);
        *accp = acc;
      }
#pragma unroll
      for (int rr = 0; rr < 4; rr++) {
        int lrow = m * 16 + kq * 4 + rr;
        size_t row = row0 + lrow;
        float si = fsigmoid(ai[rr]);
        float sf = fsigmoid(af[rr]);
        float gv = ftanh_f(ag[rr]);
        float so = fsigmoid(ao[rr]);
        float cn = sf * c_pre[m][rr] + si * gv;
        float hv = so * ftanh_f(cn);
        if (j < 50) {
          out[row * OUTC + 274 + j] = cn;
          out[row * OUTC + 224 + j] = hv;
        }
        hn[lrow * 72 + j] = (bf16_t)((j < 50) ? hv : 0.f);
      }
    }
  }
  __syncthreads();

  // zero hm pad cols 176:192 (old agg data) — no reader until S8, barrier-protected
  if (tid < 64) {
    int row = tid >> 1, c = 176 + (tid & 1) * 8;
    bf16x8 z = {};
    *(bf16x8*)(hm + row * 264 + c) = z;
  }

  // ---- Stage 6: h2a = relu(h_new @ W_u1^T + b_u1) -> t1[:,0:112] ----
  {
    bf16x8 ah[2][2];
#pragma unroll
    for (int m = 0; m < 2; m++)
#pragma unroll
      for (int k = 0; k < 2; k++)
        ah[m][k] = *(const bf16x8*)(hn + (m * 16 + lr) * 72 + kq * 8 + k * 32);
    for (int nt = w; nt < 7; nt += 4) {
      int nb = nt * 16;
      float bv = (nb + lr < 100) ? b_u1[nb + lr] : 0.f;
      const bf16_t* Bp = wb + OFF_WU1 + (nb + lr) * 64 + kq * 8;
      bf16x8 b0 = *(const bf16x8*)Bp;
      bf16x8 b1 = *(const bf16x8*)(Bp + 32);
#pragma unroll
      for (int m = 0; m < 2; m++) {
        f32x4 acc = {bv, bv, bv, bv};
        acc = MFMA(ah[m][0], b0, acc);
        acc = MFMA(ah[m][1], b1, acc);
#pragma unroll
        for (int rr = 0; rr < 4; rr++)
          t1[(m * 16 + kq * 4 + rr) * 136 + nb + lr] = (bf16_t)fmaxf(acc[rr], 0.f);
      }
    }
  }
  __syncthreads();

  // ---- Stage 7: h2b = relu(h2a @ W_u2^T + b_u2) -> hm[:,64:176] ----
  for (int nt = w; nt < 7; nt += 4) {
    int nb = nt * 16;
    float bv = (nb + lr < 100) ? b_u2[nb + lr] : 0.f;
    const bf16_t* Bp = wb + OFF_WU2 + (nb + lr) * 128 + kq * 8;
    bf16x8 bb[4];
#pragma unroll
    for (int k = 0; k < 4; k++) bb[k] = *(const bf16x8*)(Bp + k * 32);
#pragma unroll
    for (int m = 0; m < 2; m++) {
      f32x4 acc = {bv, bv, bv, bv};
#pragma unroll
      for (int k = 0; k < 4; k++) {
        bf16x8 a = *(const bf16x8*)(t1 + (m * 16 + lr) * 136 + kq * 8 + k * 32);
        acc = MFMA(a, bb[k], acc);
      }
#pragma unroll
      for (int rr = 0; rr < 4; rr++)
        hm[(m * 16 + kq * 4 + rr) * 264 + 64 + nb + lr] = (bf16_t)fmaxf(acc[rr], 0.f);
    }
  }
  __syncthreads();

  // ---- Stage 8: h2 = h2b @ W_u3^T + b_u3 -> out[:,160:224] and t1[:,0:64] ----
  {
    int nb = w * 16;
    float bv = b_u3[nb + lr];
    const bf16_t* Bp = wb + OFF_WU3 + (nb + lr) * 128 + kq * 8;
    bf16x8 bb[4];
#pragma unroll
    for (int k = 0; k < 4; k++) bb[k] = *(const bf16x8*)(Bp + k * 32);
#pragma unroll
    for (int m = 0; m < 2; m++) {
      f32x4 acc = {bv, bv, bv, bv};
#pragma unroll
      for (int k = 0; k < 4; k++) {
        bf16x8 a = *(const bf16x8*)(hm + (m * 16 + lr) * 264 + 64 + kq * 8 + k * 32);
        acc = MFMA(a, bb[k], acc);
      }
#pragma unroll
      for (int rr = 0; rr < 4; rr++) {
        int lrow = m * 16 + kq * 4 + rr;
        size_t row = row0 + lrow;
        out[row * OUTC + 160 + nb + lr] = acc[rr];
        t1[lrow * 136 + nb + lr] = (bf16_t)acc[rr];
      }
    }
  }
  __syncthreads();

  // ---- Stage 9: mu / var heads. wave: m = w&1, head = w>>1 ----
  {
    int m = w & 1, head = w >> 1;
    const bf16_t* Bp = wb + OFF_WMV + head * 16 * 64 + lr * 64 + kq * 8;
    bf16x8 b0 = *(const bf16x8*)Bp;
    bf16x8 b1 = *(const bf16x8*)(Bp + 32);
    bf16x8 a0 = *(const bf16x8*)(t1 + (m * 16 + lr) * 136 + kq * 8);
    bf16x8 a1 = *(const bf16x8*)(t1 + (m * 16 + lr) * 136 + kq * 8 + 32);
    if (head == 0) {
      float bv = b_mu[lr];
      f32x4 acc = {bv, bv, bv, bv};
      acc = MFMA(a0, b0, acc);
      acc = MFMA(a1, b1, acc);
#pragma unroll
      for (int rr = 0; rr < 4; rr++) {
        size_t row = row0 + m * 16 + kq * 4 + rr;
        out[row * OUTC + lr] = acc[rr];
      }
    } else {
      float bv = b_var[lr];
      f32x4 acc = {bv, bv, bv, bv};
      acc = MFMA(a0, b0, acc);
      acc = MFMA(a1, b1, acc);
      float mx = maxlv[lr], mn = minlv[lr];
#pragma unroll
      for (int rr = 0; rr < 4; rr++) {
        size_t row = row0 + m * 16 + kq * 4 + rr;
        float lv = acc[rr];
        lv = mx - fsoftplus(mx - lv);
        lv = mn + fsoftplus(lv - mn);
        out[row * OUTC + 16 + lr] = __expf(lv);
      }
    }
  }
}

extern "C" void kernel_launch(void* const* d_in, const int* in_sizes, int n_in,
                              void* d_out, int out_size, void* d_ws, size_t ws_size,
                              hipStream_t stream) {
  const float* obs   = (const float*)d_in[0];
  const float* msgs  = (const float*)d_in[1];
  const float* h_l   = (const float*)d_in[2];
  const float* c_l   = (const float*)d_in[3];
  const float* W_in  = (const float*)d_in[4];
  const float* b_in  = (const float*)d_in[5];
  const float* mW1   = (const float*)d_in[6];
  const float* mb1   = (const float*)d_in[7];
  const float* mW2   = (const float*)d_in[8];
  const float* mb2   = (const float*)d_in[9];
  const float* W_ih  = (const float*)d_in[10];
  const float* W_hh  = (const float*)d_in[11];
  const float* b_ih  = (const float*)d_in[12];
  const float* b_hh  = (const float*)d_in[13];
  const float* W_u1  = (const float*)d_in[14];
  const float* b_u1  = (const float*)d_in[15];
  const float* W_u2  = (const float*)d_in[16];
  const float* b_u2  = (const float*)d_in[17];
  const float* W_u3  = (const float*)d_in[18];
  const float* b_u3  = (const float*)d_in[19];
  const float* W_mu  = (const float*)d_in[20];
  const float* b_mu  = (const float*)d_in[21];
  const float* W_var = (const float*)d_in[22];
  const float* b_var = (const float*)d_in[23];
  const float* maxlv = (const float*)d_in[24];
  const float* minlv = (const float*)d_in[25];

  bf16_t* wb = (bf16_t*)d_ws;
  float* bg = (float*)((char*)d_ws + (size_t)BF16_TOTAL * 2);

  prep_kernel<<<64, 256, 0, stream>>>(W_in, mW1, mW2, W_ih, W_hh, b_ih, b_hh,
                                      W_u1, W_u2, W_u3, W_mu, W_var, wb, bg);
  fused_kernel<<<B_TOTAL / ROWS, 256, 0, stream>>>(
      obs, msgs, h_l, c_l, b_in, mb1, mb2, b_u1, b_u2, b_u3,
      b_mu, b_var, maxlv, minlv, wb, bg, (float*)d_out);
}

// Round 3
// 449.119 us; speedup vs baseline: 1.1332x; 1.1332x over previous
//
#include <hip/hip_runtime.h>

typedef __bf16 bf16_t;
typedef __bf16 bf16x8 __attribute__((ext_vector_type(8)));
typedef float f32x4 __attribute__((ext_vector_type(4)));

#define B_TOTAL 262144
#define OUTC 324
#define ROWS 64

// d_ws layout (bf16 element offsets)
#define OFF_WIN   0        // [64][32]
#define OFF_WG    2048     // [256][256] gate-major: n = g*64 + j
#define OFF_WM1   67584    // [4][112][64]
#define OFF_WM2   96256    // [4][32][128]
#define OFF_WU1   112640   // [112][64]
#define OFF_WU2   119808   // [112][128]
#define OFF_WU3   134144   // [64][128]
#define OFF_WMV   142336   // [32][64]  (mu rows 0:16, var rows 16:32)
#define BF16_TOTAL 144384
// f32 combined gate bias bg[256] at byte offset BF16_TOTAL*2

__global__ void prep_kernel(const float* W_in, const float* msg_W1, const float* msg_W2,
                            const float* W_ih, const float* W_hh, const float* b_ih, const float* b_hh,
                            const float* W_u1, const float* W_u2, const float* W_u3,
                            const float* W_mu, const float* W_var,
                            bf16_t* wb, float* bg) {
  int tid = blockIdx.x * blockDim.x + threadIdx.x;
  int nth = gridDim.x * blockDim.x;
  for (int i = tid; i < 2048; i += nth) wb[OFF_WIN + i] = (bf16_t)W_in[i];
  for (int i = tid; i < 65536; i += nth) {
    int n = i >> 8, k = i & 255;
    int g = n >> 6, j = n & 63;
    float v = 0.f;
    if (j < 50) {
      int r = g * 50 + j;
      if (k < 192) v = W_ih[r * 192 + k];
      else if (k < 242) v = W_hh[r * 50 + (k - 192)];
    }
    wb[OFF_WG + i] = (bf16_t)v;
  }
  for (int i = tid; i < 256; i += nth) {
    int g = i >> 6, j = i & 63;
    bg[i] = (j < 50) ? (b_ih[g * 50 + j] + b_hh[g * 50 + j]) : 0.f;
  }
  for (int i = tid; i < 4 * 112 * 64; i += nth) {
    int p = i / (112 * 64); int rem = i % (112 * 64); int n = rem >> 6, k = rem & 63;
    wb[OFF_WM1 + i] = (bf16_t)((n < 100) ? msg_W1[(p * 100 + n) * 64 + k] : 0.f);
  }
  for (int i = tid; i < 4 * 32 * 128; i += nth) {
    int p = i / (32 * 128); int rem = i % (32 * 128); int n = rem >> 7, k = rem & 127;
    wb[OFF_WM2 + i] = (bf16_t)((k < 100) ? msg_W2[(p * 32 + n) * 100 + k] : 0.f);
  }
  for (int i = tid; i < 112 * 64; i += nth) {
    int n = i >> 6, k = i & 63;
    wb[OFF_WU1 + i] = (bf16_t)((n < 100 && k < 50) ? W_u1[n * 50 + k] : 0.f);
  }
  for (int i = tid; i < 112 * 128; i += nth) {
    int n = i >> 7, k = i & 127;
    wb[OFF_WU2 + i] = (bf16_t)((n < 100 && k < 100) ? W_u2[n * 100 + k] : 0.f);
  }
  for (int i = tid; i < 64 * 128; i += nth) {
    int n = i >> 7, k = i & 127;
    wb[OFF_WU3 + i] = (bf16_t)((k < 100) ? W_u3[n * 100 + k] : 0.f);
  }
  for (int i = tid; i < 32 * 64; i += nth) {
    int n = i >> 6, k = i & 63;
    wb[OFF_WMV + i] = (bf16_t)((n < 16) ? W_mu[n * 64 + k] : W_var[(n - 16) * 64 + k]);
  }
}

#define MFMA(a, b, c) __builtin_amdgcn_mfma_f32_16x16x32_bf16((a), (b), (c), 0, 0, 0)

__device__ __forceinline__ float frcp(float x) { return __builtin_amdgcn_rcpf(x); }
__device__ __forceinline__ float fsigmoid(float x) { return frcp(1.f + __expf(-x)); }
__device__ __forceinline__ float ftanh_f(float x) { return 1.f - 2.f * frcp(1.f + __expf(2.f * x)); }
__device__ __forceinline__ float fsoftplus(float x) { return (x > 15.f) ? x : __logf(1.f + __expf(x)); }

__device__ __forceinline__ bf16x8 cvt8(const float* __restrict__ p) {
  float4 v0 = *(const float4*)p;
  float4 v1 = *(const float4*)(p + 4);
  bf16x8 r;
  r[0] = (bf16_t)v0.x; r[1] = (bf16_t)v0.y; r[2] = (bf16_t)v0.z; r[3] = (bf16_t)v0.w;
  r[4] = (bf16_t)v1.x; r[5] = (bf16_t)v1.y; r[6] = (bf16_t)v1.z; r[7] = (bf16_t)v1.w;
  return r;
}

// LDS buffers: xb[64][72] (x -> h2), t1a[64][120] (m1 -> hn -> h2b), t1b[64][120] (h -> h2a)
__global__ __launch_bounds__(256, 4) void fused_kernel(
    const float* __restrict__ obs, const float* __restrict__ msg_in,
    const float* __restrict__ h_lstm, const float* __restrict__ c_lstm,
    const float* __restrict__ b_in, const float* __restrict__ msg_b1,
    const float* __restrict__ msg_b2, const float* __restrict__ b_u1,
    const float* __restrict__ b_u2, const float* __restrict__ b_u3,
    const float* __restrict__ b_mu, const float* __restrict__ b_var,
    const float* __restrict__ maxlv, const float* __restrict__ minlv,
    const bf16_t* __restrict__ wb, const float* __restrict__ bg,
    float* __restrict__ out) {
  __shared__ __align__(16) bf16_t xb[ROWS * 72];
  __shared__ __align__(16) bf16_t t1a[ROWS * 120];
  __shared__ __align__(16) bf16_t t1b[ROWS * 120];

  const int tid = threadIdx.x;
  const int row0 = blockIdx.x * ROWS;
  const int lane = tid & 63;
  const int w = tid >> 6;
  const int lr = lane & 15;
  const int kq = lane >> 4;

  // ---- Stage 0: stage h_lstm -> t1b[:,0:64] (50 valid + zeros) ----
  {
    int r = tid >> 2, c0 = (tid & 3) * 16;
    const float* s = h_lstm + (size_t)(row0 + r) * 50;
    bf16x8 pk0, pk1;
#pragma unroll
    for (int q = 0; q < 8; q++) {
      int c = c0 + q;
      pk0[q] = (bf16_t)((c < 50) ? s[c] : 0.f);
    }
#pragma unroll
    for (int q = 0; q < 8; q++) {
      int c = c0 + 8 + q;
      pk1[q] = (bf16_t)((c < 50) ? s[c] : 0.f);
    }
    *(bf16x8*)(t1b + r * 120 + c0) = pk0;
    *(bf16x8*)(t1b + r * 120 + c0 + 8) = pk1;
  }

  // ---- Stage 1: x = relu(obs @ W_in^T + b_in) -> xb ----
  {
    int nb = w * 16;
    float bv = b_in[nb + lr];
    bf16x8 b0 = *(const bf16x8*)(wb + OFF_WIN + (nb + lr) * 32 + kq * 8);
#pragma unroll
    for (int m = 0; m < 4; m++) {
      bf16x8 a0 = cvt8(obs + (size_t)(row0 + m * 16 + lr) * 32 + kq * 8);
      f32x4 acc = {bv, bv, bv, bv};
      acc = MFMA(a0, b0, acc);
#pragma unroll
      for (int rr = 0; rr < 4; rr++)
        xb[(m * 16 + kq * 4 + rr) * 72 + nb + lr] = (bf16_t)fmaxf(acc[rr], 0.f);
    }
  }
  __syncthreads();

  // ---- Stages 2/3 per port ----
  for (int p = 0; p < 4; p++) {
    // S2: m1 = relu(x @ W1^T + b1) -> t1a[:,0:112]
    for (int nt = w; nt < 7; nt += 4) {
      int nb = nt * 16;
      float bv = (nb + lr < 100) ? msg_b1[p * 100 + nb + lr] : 0.f;
      const bf16_t* Bp = wb + OFF_WM1 + p * 112 * 64 + (nb + lr) * 64 + kq * 8;
      bf16x8 b0 = *(const bf16x8*)Bp;
      bf16x8 b1 = *(const bf16x8*)(Bp + 32);
#pragma unroll
      for (int m = 0; m < 4; m++) {
        bf16x8 a0 = *(const bf16x8*)(xb + (m * 16 + lr) * 72 + kq * 8);
        bf16x8 a1 = *(const bf16x8*)(xb + (m * 16 + lr) * 72 + kq * 8 + 32);
        f32x4 acc = {bv, bv, bv, bv};
        acc = MFMA(a0, b0, acc);
        acc = MFMA(a1, b1, acc);
#pragma unroll
        for (int rr = 0; rr < 4; rr++)
          t1a[(m * 16 + kq * 4 + rr) * 120 + nb + lr] = (bf16_t)fmaxf(acc[rr], 0.f);
      }
    }
    __syncthreads();
    // S3: msgs = m1 @ W2^T + b2 -> out[:, 32+32p : 64+32p]
    {
      int nb = (w & 1) * 16;
      float bv = msg_b2[p * 32 + nb + lr];
      const bf16_t* Bp = wb + OFF_WM2 + p * 32 * 128 + (nb + lr) * 128 + kq * 8;
      bf16x8 b[4];
#pragma unroll
      for (int c = 0; c < 4; c++) b[c] = *(const bf16x8*)(Bp + c * 32);
#pragma unroll
      for (int mi = 0; mi < 2; mi++) {
        int m = (w >> 1) + mi * 2;
        f32x4 acc = {bv, bv, bv, bv};
#pragma unroll
        for (int c = 0; c < 4; c++) {
          bf16x8 a;
          if (c < 3) {
            a = *(const bf16x8*)(t1a + (m * 16 + lr) * 120 + c * 32 + kq * 8);
          } else {
            bf16x8 z = {};
            a = (kq < 2) ? *(const bf16x8*)(t1a + (m * 16 + lr) * 120 + 96 + kq * 8) : z;
          }
          acc = MFMA(a, b[c], acc);
        }
#pragma unroll
        for (int rr = 0; rr < 4; rr++) {
          size_t row = row0 + m * 16 + kq * 4 + rr;
          out[row * OUTC + 32 + p * 32 + nb + lr] = acc[rr];
        }
      }
    }
    __syncthreads();
  }

  // ---- Stage 4: gates (K=256) + LSTM cell ----
  // wave w: mt = w>>1 (rows mt*32..+32), jh = w&1 (j in [32jh, 32jh+32))
  {
    const int mt = w >> 1, jh = w & 1;
    f32x4 acc[4][2][2];  // [gate][s: j-subtile][msub: row-subtile]
#pragma unroll
    for (int g = 0; g < 4; g++)
#pragma unroll
      for (int s = 0; s < 2; s++) {
        float bb = bg[g * 64 + jh * 32 + s * 16 + lr];
        f32x4 bi = {bb, bb, bb, bb};
        acc[g][s][0] = bi;
        acc[g][s][1] = bi;
      }
#pragma unroll
    for (int c = 0; c < 8; c++) {
      bf16x8 a[2];
#pragma unroll
      for (int ms = 0; ms < 2; ms++) {
        int row = mt * 32 + ms * 16 + lr;
        if (c < 2) {
          a[ms] = *(const bf16x8*)(xb + row * 72 + c * 32 + kq * 8);
        } else if (c < 6) {
          int p = c - 2;
          a[ms] = cvt8(msg_in + ((size_t)p * B_TOTAL + row0 + row) * 32 + kq * 8);
        } else {
          a[ms] = *(const bf16x8*)(t1b + row * 120 + (c - 6) * 32 + kq * 8);
        }
      }
#pragma unroll
      for (int g = 0; g < 4; g++)
#pragma unroll
        for (int s = 0; s < 2; s++) {
          bf16x8 bfrag = *(const bf16x8*)(wb + OFF_WG +
              (size_t)(g * 64 + jh * 32 + s * 16 + lr) * 256 + c * 32 + kq * 8);
          acc[g][s][0] = MFMA(a[0], bfrag, acc[g][s][0]);
          acc[g][s][1] = MFMA(a[1], bfrag, acc[g][s][1]);
        }
    }
    // LSTM elementwise epilogue; hn -> t1a[:,0:64]
#pragma unroll
    for (int s = 0; s < 2; s++) {
      int j = jh * 32 + s * 16 + lr;
#pragma unroll
      for (int ms = 0; ms < 2; ms++) {
        int rbase = mt * 32 + ms * 16 + kq * 4;
#pragma unroll
        for (int rr = 0; rr < 4; rr++) {
          int lrow = rbase + rr;
          size_t row = row0 + lrow;
          float c_old = (j < 50) ? c_lstm[row * 50 + j] : 0.f;
          float si = fsigmoid(acc[0][s][ms][rr]);
          float sf = fsigmoid(acc[1][s][ms][rr]);
          float gv = ftanh_f(acc[2][s][ms][rr]);
          float so = fsigmoid(acc[3][s][ms][rr]);
          float cn = sf * c_old + si * gv;
          float hv = so * ftanh_f(cn);
          if (j < 50) {
            out[row * OUTC + 274 + j] = cn;
            out[row * OUTC + 224 + j] = hv;
          }
          t1a[lrow * 120 + j] = (bf16_t)((j < 50) ? hv : 0.f);
        }
      }
    }
  }
  __syncthreads();

  // ---- Stage 6: h2a = relu(hn @ Wu1^T + b_u1) -> t1b[:,0:112] ----
  for (int nt = w; nt < 7; nt += 4) {
    int nb = nt * 16;
    float bv = (nb + lr < 100) ? b_u1[nb + lr] : 0.f;
    const bf16_t* Bp = wb + OFF_WU1 + (nb + lr) * 64 + kq * 8;
    bf16x8 b0 = *(const bf16x8*)Bp;
    bf16x8 b1 = *(const bf16x8*)(Bp + 32);
#pragma unroll
    for (int m = 0; m < 4; m++) {
      bf16x8 a0 = *(const bf16x8*)(t1a + (m * 16 + lr) * 120 + kq * 8);
      bf16x8 a1 = *(const bf16x8*)(t1a + (m * 16 + lr) * 120 + kq * 8 + 32);
      f32x4 acc = {bv, bv, bv, bv};
      acc = MFMA(a0, b0, acc);
      acc = MFMA(a1, b1, acc);
#pragma unroll
      for (int rr = 0; rr < 4; rr++)
        t1b[(m * 16 + kq * 4 + rr) * 120 + nb + lr] = (bf16_t)fmaxf(acc[rr], 0.f);
    }
  }
  __syncthreads();

  // ---- Stage 7: h2b = relu(h2a @ Wu2^T + b_u2) -> t1a[:,0:112] ----
  for (int nt = w; nt < 7; nt += 4) {
    int nb = nt * 16;
    float bv = (nb + lr < 100) ? b_u2[nb + lr] : 0.f;
    const bf16_t* Bp = wb + OFF_WU2 + (nb + lr) * 128 + kq * 8;
    bf16x8 b[4];
#pragma unroll
    for (int c = 0; c < 4; c++) b[c] = *(const bf16x8*)(Bp + c * 32);
#pragma unroll
    for (int m = 0; m < 4; m++) {
      f32x4 acc = {bv, bv, bv, bv};
#pragma unroll
      for (int c = 0; c < 4; c++) {
        bf16x8 a;
        if (c < 3) {
          a = *(const bf16x8*)(t1b + (m * 16 + lr) * 120 + c * 32 + kq * 8);
        } else {
          bf16x8 z = {};
          a = (kq < 2) ? *(const bf16x8*)(t1b + (m * 16 + lr) * 120 + 96 + kq * 8) : z;
        }
        acc = MFMA(a, b[c], acc);
      }
#pragma unroll
      for (int rr = 0; rr < 4; rr++)
        t1a[(m * 16 + kq * 4 + rr) * 120 + nb + lr] = (bf16_t)fmaxf(acc[rr], 0.f);
    }
  }
  __syncthreads();

  // ---- Stage 8: h2 = h2b @ Wu3^T + b_u3 -> out[:,160:224] and xb[:,0:64] ----
  {
    int nb = w * 16;
    float bv = b_u3[nb + lr];
    const bf16_t* Bp = wb + OFF_WU3 + (nb + lr) * 128 + kq * 8;
    bf16x8 b[4];
#pragma unroll
    for (int c = 0; c < 4; c++) b[c] = *(const bf16x8*)(Bp + c * 32);
#pragma unroll
    for (int m = 0; m < 4; m++) {
      f32x4 acc = {bv, bv, bv, bv};
#pragma unroll
      for (int c = 0; c < 4; c++) {
        bf16x8 a;
        if (c < 3) {
          a = *(const bf16x8*)(t1a + (m * 16 + lr) * 120 + c * 32 + kq * 8);
        } else {
          bf16x8 z = {};
          a = (kq < 2) ? *(const bf16x8*)(t1a + (m * 16 + lr) * 120 + 96 + kq * 8) : z;
        }
        acc = MFMA(a, b[c], acc);
      }
#pragma unroll
      for (int rr = 0; rr < 4; rr++) {
        int lrow = m * 16 + kq * 4 + rr;
        size_t row = row0 + lrow;
        out[row * OUTC + 160 + nb + lr] = acc[rr];
        xb[lrow * 72 + nb + lr] = (bf16_t)acc[rr];
      }
    }
  }
  __syncthreads();

  // ---- Stage 9: mu / var heads ----
  {
    int head = w & 1;
    const bf16_t* Bp = wb + OFF_WMV + head * 16 * 64 + lr * 64 + kq * 8;
    bf16x8 b0 = *(const bf16x8*)Bp;
    bf16x8 b1 = *(const bf16x8*)(Bp + 32);
    float bv = head ? b_var[lr] : b_mu[lr];
    float mx = maxlv[lr], mn = minlv[lr];
#pragma unroll
    for (int mi = 0; mi < 2; mi++) {
      int m = (w >> 1) + mi * 2;
      bf16x8 a0 = *(const bf16x8*)(xb + (m * 16 + lr) * 72 + kq * 8);
      bf16x8 a1 = *(const bf16x8*)(xb + (m * 16 + lr) * 72 + kq * 8 + 32);
      f32x4 acc = {bv, bv, bv, bv};
      acc = MFMA(a0, b0, acc);
      acc = MFMA(a1, b1, acc);
      if (head == 0) {
#pragma unroll
        for (int rr = 0; rr < 4; rr++) {
          size_t row = row0 + m * 16 + kq * 4 + rr;
          out[row * OUTC + lr] = acc[rr];
        }
      } else {
#pragma unroll
        for (int rr = 0; rr < 4; rr++) {
          size_t row = row0 + m * 16 + kq * 4 + rr;
          float lv = acc[rr];
          lv = mx - fsoftplus(mx - lv);
          lv = mn + fsoftplus(lv - mn);
          out[row * OUTC + 16 + lr] = __expf(lv);
        }
      }
    }
  }
}

extern "C" void kernel_launch(void* const* d_in, const int* in_sizes, int n_in,
                              void* d_out, int out_size, void* d_ws, size_t ws_size,
                              hipStream_t stream) {
  const float* obs   = (const float*)d_in[0];
  const float* msgs  = (const float*)d_in[1];
  const float* h_l   = (const float*)d_in[2];
  const float* c_l   = (const float*)d_in[3];
  const float* W_in  = (const float*)d_in[4];
  const float* b_in  = (const float*)d_in[5];
  const float* mW1   = (const float*)d_in[6];
  const float* mb1   = (const float*)d_in[7];
  const float* mW2   = (const float*)d_in[8];
  const float* mb2   = (const float*)d_in[9];
  const float* W_ih  = (const float*)d_in[10];
  const float* W_hh  = (const float*)d_in[11];
  const float* b_ih  = (const float*)d_in[12];
  const float* b_hh  = (const float*)d_in[13];
  const float* W_u1  = (const float*)d_in[14];
  const float* b_u1  = (const float*)d_in[15];
  const float* W_u2  = (const float*)d_in[16];
  const float* b_u2  = (const float*)d_in[17];
  const float* W_u3  = (const float*)d_in[18];
  const float* b_u3  = (const float*)d_in[19];
  const float* W_mu  = (const float*)d_in[20];
  const float* b_mu  = (const float*)d_in[21];
  const float* W_var = (const float*)d_in[22];
  const float* b_var = (const float*)d_in[23];
  const float* maxlv = (const float*)d_in[24];
  const float* minlv = (const float*)d_in[25];

  bf16_t* wb = (bf16_t*)d_ws;
  float* bg = (float*)((char*)d_ws + (size_t)BF16_TOTAL * 2);

  prep_kernel<<<64, 256, 0, stream>>>(W_in, mW1, mW2, W_ih, W_hh, b_ih, b_hh,
                                      W_u1, W_u2, W_u3, W_mu, W_var, wb, bg);
  fused_kernel<<<B_TOTAL / ROWS, 256, 0, stream>>>(
      obs, msgs, h_l, c_l, b_in, mb1, mb2, b_u1, b_u2, b_u3,
      b_mu, b_var, maxlv, minlv, wb, bg, (float*)d_out);
}